// Round 11
// baseline (1096.581 us; speedup 1.0000x reference)
//
#include <hip/hip_runtime.h>
#include <hip/hip_bf16.h>

#define IN_DIM  128
#define OUT_DIM 64
#define SCAN_CHUNK 1024   // 256 threads x 4 elems

// ---------------------------------------------------------------------------
// Prologue: degree histogram (also records per-edge rank) -> exclusive scan
// ---------------------------------------------------------------------------
__global__ void k_zero(unsigned* __restrict__ p, int n) {
    int i = blockIdx.x * blockDim.x + threadIdx.x;
    if (i < n) p[i] = 0u;
}

// rank[e] = number of earlier edges with same dst (atomic order; any perm ok)
__global__ void k_hist2(const int* __restrict__ dst, unsigned* __restrict__ cnt,
                        unsigned short* __restrict__ rank, int nE) {
    int e = blockIdx.x * blockDim.x + threadIdx.x;
    if (e < nE) {
        unsigned k = atomicAdd(&cnt[dst[e]], 1u);
        rank[e] = (unsigned short)k;       // sequential write
    }
}

__global__ __launch_bounds__(256) void k_scanA(const unsigned* __restrict__ cnt,
                                               unsigned* __restrict__ offs,
                                               unsigned* __restrict__ partials,
                                               float* __restrict__ dinv, int n) {
    __shared__ unsigned sums[256];
    int base = blockIdx.x * SCAN_CHUNK + threadIdx.x * 4;
    unsigned v[4]; unsigned s = 0;
#pragma unroll
    for (int k = 0; k < 4; ++k) {
        int i = base + k;
        unsigned c = (i < n) ? cnt[i] : 0u;
        if (i < n) dinv[i] = rsqrtf((float)c + 1.0f);   // +1 self-loop
        v[k] = s; s += c;
    }
    sums[threadIdx.x] = s;
    __syncthreads();
    for (int d = 1; d < 256; d <<= 1) {
        unsigned t = (threadIdx.x >= (unsigned)d) ? sums[threadIdx.x - d] : 0u;
        __syncthreads();
        sums[threadIdx.x] += t;
        __syncthreads();
    }
    unsigned excl = sums[threadIdx.x] - s;
#pragma unroll
    for (int k = 0; k < 4; ++k) {
        int i = base + k;
        if (i < n) offs[i] = excl + v[k];
    }
    if (threadIdx.x == 255) partials[blockIdx.x] = sums[255];
}

__global__ void k_scanB(unsigned* __restrict__ partials, int nb) {
    __shared__ unsigned s[256];
    unsigned v = (threadIdx.x < (unsigned)nb) ? partials[threadIdx.x] : 0u;
    s[threadIdx.x] = v;
    __syncthreads();
    for (int d = 1; d < 256; d <<= 1) {
        unsigned t = (threadIdx.x >= (unsigned)d) ? s[threadIdx.x - d] : 0u;
        __syncthreads();
        s[threadIdx.x] += t;
        __syncthreads();
    }
    if (threadIdx.x < (unsigned)nb) partials[threadIdx.x] = s[threadIdx.x] - v;
}

__global__ void k_scanC(unsigned* __restrict__ offs, const unsigned* __restrict__ partials,
                        int n) {
    int i = blockIdx.x * blockDim.x + threadIdx.x;
    if (i < n) offs[i] += partials[i / SCAN_CHUNK];
}

// ---------------------------------------------------------------------------
// Atomic-free edge scatter (LDS-free, high occupancy hides write latency)
// ---------------------------------------------------------------------------
__global__ void k_scat(const int* __restrict__ src, const int* __restrict__ dst,
                       const unsigned short* __restrict__ rank,
                       const unsigned* __restrict__ offs,
                       int* __restrict__ perm, int nE) {
    int e = blockIdx.x * blockDim.x + threadIdx.x;
    if (e < nE) {
        unsigned p = offs[dst[e]] + (unsigned)rank[e];
        __builtin_nontemporal_store(src[e], &perm[p]);
    }
}

// ---------------------------------------------------------------------------
// Linear layer: x-tile staged in LDS (coalesced), W read GLOBAL-direct into
// 32 per-lane VGPRs per K-chunk (coalesced, L1/L2-hot) -- W never touches
// LDS (R7's dominant LDS cost was staging 32KiB of W per 32-row block).
// 256 thr / 32-row tile / 8 rows per wave; LDS 16KiB (KD=128) -> 32 waves/CU.
// RELU folds relu(dinv*in) into staging (layer-2 input).
// Output bf16 (RNE): halves the downstream gather's random-row traffic.
// ---------------------------------------------------------------------------
template <int KD, bool RELU>
__global__ __launch_bounds__(256) void k_lin(const float* __restrict__ in,
                                             const float* __restrict__ W,    // [KD][64]
                                             const float* __restrict__ dinv,
                                             __hip_bfloat16* __restrict__ outp, int n) {
    __shared__ float xs[32 * KD];        // 16 KiB (KD=128) / 8 KiB (KD=64)
    int r0t = blockIdx.x * 32;
    const int F4 = 32 * KD / 4;
    const float4* gin = (const float4*)(in + (size_t)r0t * KD);
    for (int f = threadIdx.x; f < F4; f += 256) {
        int row = r0t + f / (KD / 4);
        float4 v = {0.f, 0.f, 0.f, 0.f};
        if (row < n) {
            v = gin[f];                  // coalesced: lanes -> consecutive 16B
            if (RELU) {
                float dv = dinv[row];
                v.x = fmaxf(dv * v.x, 0.f); v.y = fmaxf(dv * v.y, 0.f);
                v.z = fmaxf(dv * v.z, 0.f); v.w = fmaxf(dv * v.w, 0.f);
            }
        }
        ((float4*)xs)[f] = v;
    }
    __syncthreads();

    int wid = threadIdx.x >> 6, lane = threadIdx.x & 63;
    int r0 = wid * 8;                    // 8 rows per wave
    float acc[8] = {0.f, 0.f, 0.f, 0.f, 0.f, 0.f, 0.f, 0.f};
#pragma unroll
    for (int ch = 0; ch < KD / 32; ++ch) {
        float wr[32];                    // W chunk in registers (per lane = column)
#pragma unroll
        for (int k = 0; k < 32; ++k)
            wr[k] = W[(size_t)(ch * 32 + k) * 64 + lane];   // coalesced global
#pragma unroll
        for (int r = 0; r < 8; ++r) {
#pragma unroll
            for (int q = 0; q < 8; ++q) {
                float4 xv = *(const float4*)&xs[(r0 + r) * KD + ch * 32 + 4 * q]; // LDS broadcast
                acc[r] += xv.x * wr[4 * q + 0] + xv.y * wr[4 * q + 1]
                        + xv.z * wr[4 * q + 2] + xv.w * wr[4 * q + 3];
            }
        }
    }
#pragma unroll
    for (int r = 0; r < 8; ++r) {
        int row = r0t + r0 + r;
        if (row < n)
            outp[(size_t)row * 64 + lane] = __float2bfloat16(dinv[row] * acc[r]);
    }
}

// ---------------------------------------------------------------------------
// CSR gather, 8-way ILP: one wave per node, lane = feature dim.
// hs rows are bf16 (128B/row -> 1 line per random gather). Accumulate f32.
// acc = hs[r] (self-loop) + sum over neighbors; FIN applies final dinv[r].
// ---------------------------------------------------------------------------
template <bool FIN>
__global__ __launch_bounds__(256) void k_gather(const __hip_bfloat16* __restrict__ hs,
                                                const unsigned* __restrict__ offs,
                                                const int* __restrict__ perm,
                                                const float* __restrict__ dinv,
                                                float* __restrict__ outb,
                                                int n, int nE) {
    int lane = threadIdx.x & 63;
    int r = blockIdx.x * 4 + (threadIdx.x >> 6);
    if (r >= n) return;
    unsigned beg = offs[r];
    unsigned end = (r + 1 < n) ? offs[r + 1] : (unsigned)nE;
    float a0 = __bfloat162float(hs[(size_t)r * 64 + lane]);   // self-loop term
    float a1 = 0.f, a2 = 0.f, a3 = 0.f, a4 = 0.f, a5 = 0.f, a6 = 0.f, a7 = 0.f;
    for (unsigned e0 = beg; e0 < end; e0 += 64) {
        unsigned c = min(64u, end - e0);
        int sl = (lane < (int)c) ? perm[e0 + lane] : 0;       // coalesced edge read
        unsigned k = 0;
        for (; k + 8 <= c; k += 8) {
            int s0 = __shfl(sl, (int)k);
            int s1 = __shfl(sl, (int)k + 1);
            int s2 = __shfl(sl, (int)k + 2);
            int s3 = __shfl(sl, (int)k + 3);
            int s4 = __shfl(sl, (int)k + 4);
            int s5 = __shfl(sl, (int)k + 5);
            int s6 = __shfl(sl, (int)k + 6);
            int s7 = __shfl(sl, (int)k + 7);
            float v0 = __bfloat162float(hs[(size_t)s0 * 64 + lane]);
            float v1 = __bfloat162float(hs[(size_t)s1 * 64 + lane]);
            float v2 = __bfloat162float(hs[(size_t)s2 * 64 + lane]);
            float v3 = __bfloat162float(hs[(size_t)s3 * 64 + lane]);
            float v4 = __bfloat162float(hs[(size_t)s4 * 64 + lane]);
            float v5 = __bfloat162float(hs[(size_t)s5 * 64 + lane]);
            float v6 = __bfloat162float(hs[(size_t)s6 * 64 + lane]);
            float v7 = __bfloat162float(hs[(size_t)s7 * 64 + lane]);
            a0 += v0; a1 += v1; a2 += v2; a3 += v3;
            a4 += v4; a5 += v5; a6 += v6; a7 += v7;
        }
        for (; k + 4 <= c; k += 4) {
            int s0 = __shfl(sl, (int)k);
            int s1 = __shfl(sl, (int)k + 1);
            int s2 = __shfl(sl, (int)k + 2);
            int s3 = __shfl(sl, (int)k + 3);
            float v0 = __bfloat162float(hs[(size_t)s0 * 64 + lane]);
            float v1 = __bfloat162float(hs[(size_t)s1 * 64 + lane]);
            float v2 = __bfloat162float(hs[(size_t)s2 * 64 + lane]);
            float v3 = __bfloat162float(hs[(size_t)s3 * 64 + lane]);
            a0 += v0; a1 += v1; a2 += v2; a3 += v3;
        }
        for (; k < c; ++k) {
            int s = __shfl(sl, (int)k);
            a0 += __bfloat162float(hs[(size_t)s * 64 + lane]);
        }
    }
    float acc = ((a0 + a1) + (a2 + a3)) + ((a4 + a5) + (a6 + a7));
    if (FIN) acc *= dinv[r];
    outb[(size_t)r * 64 + lane] = acc;
}

// ---------------------------------------------------------------------------
extern "C" void kernel_launch(void* const* d_in, const int* in_sizes, int n_in,
                              void* d_out, int out_size, void* d_ws, size_t ws_size,
                              hipStream_t stream) {
    const float* x  = (const float*)d_in[0];
    const int*   ei = (const int*)d_in[1];
    const float* W1 = (const float*)d_in[2];
    const float* W2 = (const float*)d_in[3];
    float* out = (float*)d_out;

    int n  = in_sizes[0] / IN_DIM;   // 100000
    int nE = in_sizes[1] / 2;        // 1600000
    const int* src = ei;
    const int* dst = ei + nE;

    // workspace carve-up (256B-aligned); d_out doubles as the layer-1 agg buffer
    char* w = (char*)d_ws;
    size_t nAl = ((size_t)n * 4 + 255) & ~(size_t)255;
    float*          dinv     = (float*)w;          w += nAl;
    unsigned*       cnt      = (unsigned*)w;       w += nAl;
    unsigned*       offs     = (unsigned*)w;       w += nAl;
    unsigned*       partials = (unsigned*)w;       w += 4096;
    unsigned short* rank     = (unsigned short*)w; w += ((size_t)nE * 2 + 255) & ~(size_t)255;
    int*            perm     = (int*)w;            w += ((size_t)nE * 4 + 255) & ~(size_t)255;
    __hip_bfloat16* hs       = (__hip_bfloat16*)w; w += (size_t)n * 64 * 2;   // bf16 rows
    float*          agg      = out;                // layer-1 aggregate lives in d_out

    int nb    = (n + SCAN_CHUNK - 1) / SCAN_CHUNK;
    int gE    = (nE + 255) / 256;
    int gN    = (n + 255) / 256;
    int gRow  = (n + 3) / 4;
    int gTile = (n + 31) / 32;

    // --- prologue: degrees + per-edge ranks, node offsets ---
    k_zero<<<gN, 256, 0, stream>>>(cnt, n);
    k_hist2<<<gE, 256, 0, stream>>>(dst, cnt, rank, nE);
    k_scanA<<<nb, 256, 0, stream>>>(cnt, offs, partials, dinv, n);
    k_scanB<<<1, 256, 0, stream>>>(partials, nb);
    k_scanC<<<gN, 256, 0, stream>>>(offs, partials, n);

    // --- layer 1 ---
    k_lin<IN_DIM, false><<<gTile, 256, 0, stream>>>(x, W1, dinv, hs, n);
    k_scat<<<gE, 256, 0, stream>>>(src, dst, rank, offs, perm, nE);
    k_gather<false><<<gRow, 256, 0, stream>>>(hs, offs, perm, dinv, agg, n, nE);

    // --- layer 2 (reuse hs for hs2; final dinv folded into gather) ---
    k_lin<OUT_DIM, true><<<gTile, 256, 0, stream>>>(agg, W2, dinv, hs, n);
    k_gather<true><<<gRow, 256, 0, stream>>>(hs, offs, perm, dinv, out, n, nE);
}

// Round 12
// 301.632 us; speedup vs baseline: 3.6355x; 3.6355x over previous
//
#include <hip/hip_runtime.h>
#include <hip/hip_bf16.h>

#define IN_DIM  128
#define OUT_DIM 64
#define SCAN_CHUNK 1024   // 256 threads x 4 elems

// ---------------------------------------------------------------------------
// Prologue: degree histogram (also records per-edge rank) -> exclusive scan
// ---------------------------------------------------------------------------
__global__ void k_zero(unsigned* __restrict__ p, int n) {
    int i = blockIdx.x * blockDim.x + threadIdx.x;
    if (i < n) p[i] = 0u;
}

// rank[e] = number of earlier edges with same dst (atomic order; any perm ok)
__global__ void k_hist2(const int* __restrict__ dst, unsigned* __restrict__ cnt,
                        unsigned short* __restrict__ rank, int nE) {
    int e = blockIdx.x * blockDim.x + threadIdx.x;
    if (e < nE) {
        unsigned k = atomicAdd(&cnt[dst[e]], 1u);
        rank[e] = (unsigned short)k;       // sequential write
    }
}

__global__ __launch_bounds__(256) void k_scanA(const unsigned* __restrict__ cnt,
                                               unsigned* __restrict__ offs,
                                               unsigned* __restrict__ partials,
                                               float* __restrict__ dinv, int n) {
    __shared__ unsigned sums[256];
    int base = blockIdx.x * SCAN_CHUNK + threadIdx.x * 4;
    unsigned v[4]; unsigned s = 0;
#pragma unroll
    for (int k = 0; k < 4; ++k) {
        int i = base + k;
        unsigned c = (i < n) ? cnt[i] : 0u;
        if (i < n) dinv[i] = rsqrtf((float)c + 1.0f);   // +1 self-loop
        v[k] = s; s += c;
    }
    sums[threadIdx.x] = s;
    __syncthreads();
    for (int d = 1; d < 256; d <<= 1) {
        unsigned t = (threadIdx.x >= (unsigned)d) ? sums[threadIdx.x - d] : 0u;
        __syncthreads();
        sums[threadIdx.x] += t;
        __syncthreads();
    }
    unsigned excl = sums[threadIdx.x] - s;
#pragma unroll
    for (int k = 0; k < 4; ++k) {
        int i = base + k;
        if (i < n) offs[i] = excl + v[k];
    }
    if (threadIdx.x == 255) partials[blockIdx.x] = sums[255];
}

__global__ void k_scanB(unsigned* __restrict__ partials, int nb) {
    __shared__ unsigned s[256];
    unsigned v = (threadIdx.x < (unsigned)nb) ? partials[threadIdx.x] : 0u;
    s[threadIdx.x] = v;
    __syncthreads();
    for (int d = 1; d < 256; d <<= 1) {
        unsigned t = (threadIdx.x >= (unsigned)d) ? s[threadIdx.x - d] : 0u;
        __syncthreads();
        s[threadIdx.x] += t;
        __syncthreads();
    }
    if (threadIdx.x < (unsigned)nb) partials[threadIdx.x] = s[threadIdx.x] - v;
}

__global__ void k_scanC(unsigned* __restrict__ offs, const unsigned* __restrict__ partials,
                        int n) {
    int i = blockIdx.x * blockDim.x + threadIdx.x;
    if (i < n) offs[i] += partials[i / SCAN_CHUNK];
}

// ---------------------------------------------------------------------------
// Atomic-free edge scatter (LDS-free, high occupancy hides write latency)
// ---------------------------------------------------------------------------
__global__ void k_scat(const int* __restrict__ src, const int* __restrict__ dst,
                       const unsigned short* __restrict__ rank,
                       const unsigned* __restrict__ offs,
                       int* __restrict__ perm, int nE) {
    int e = blockIdx.x * blockDim.x + threadIdx.x;
    if (e < nE) {
        unsigned p = offs[dst[e]] + (unsigned)rank[e];
        __builtin_nontemporal_store(src[e], &perm[p]);
    }
}

// ---------------------------------------------------------------------------
// Linear layer (R7-proven structure): W + 32-row x-tile staged in LDS
// (coalesced), compute reads are LDS broadcasts; 256 thr, 8 rows/wave.
// RELU folds relu(dinv*in) into staging (layer-2 input).
// Output bf16 (RNE): halves the downstream gather's random-row traffic.
// ---------------------------------------------------------------------------
template <int KD, bool RELU>
__global__ __launch_bounds__(256) void k_lin(const float* __restrict__ in,
                                             const float* __restrict__ W,   // [KD][64]
                                             const float* __restrict__ dinv,
                                             __hip_bfloat16* __restrict__ outp, int n) {
    __shared__ float Wl[KD * 64];        // 32 KiB (KD=128) / 16 KiB (KD=64)
    __shared__ float xs[32 * KD];        // 16 KiB / 8 KiB
    for (int i = threadIdx.x; i < KD * 16; i += 256)
        ((float4*)Wl)[i] = ((const float4*)W)[i];

    int r0t = blockIdx.x * 32;
    const int F4 = 32 * KD / 4;
    const float4* gin = (const float4*)(in + (size_t)r0t * KD);
    for (int f = threadIdx.x; f < F4; f += 256) {
        int row = r0t + f / (KD / 4);
        float4 v = {0.f, 0.f, 0.f, 0.f};
        if (row < n) {
            v = gin[f];                  // coalesced: lanes -> consecutive 16B
            if (RELU) {
                float dv = dinv[row];
                v.x = fmaxf(dv * v.x, 0.f); v.y = fmaxf(dv * v.y, 0.f);
                v.z = fmaxf(dv * v.z, 0.f); v.w = fmaxf(dv * v.w, 0.f);
            }
        }
        ((float4*)xs)[f] = v;
    }
    __syncthreads();

    int wid = threadIdx.x >> 6, lane = threadIdx.x & 63;
    int r0 = wid * 8;                    // 8 rows per wave
    float acc[8] = {0.f, 0.f, 0.f, 0.f, 0.f, 0.f, 0.f, 0.f};
#pragma unroll 4
    for (int k4 = 0; k4 < KD / 4; ++k4) {
        float w0 = Wl[(4 * k4 + 0) * 64 + lane];
        float w1 = Wl[(4 * k4 + 1) * 64 + lane];
        float w2 = Wl[(4 * k4 + 2) * 64 + lane];
        float w3 = Wl[(4 * k4 + 3) * 64 + lane];
#pragma unroll
        for (int r = 0; r < 8; ++r) {
            float4 xv = *(const float4*)&xs[(r0 + r) * KD + 4 * k4];  // LDS broadcast
            acc[r] += xv.x * w0 + xv.y * w1 + xv.z * w2 + xv.w * w3;
        }
    }
#pragma unroll
    for (int r = 0; r < 8; ++r) {
        int row = r0t + r0 + r;
        if (row < n)
            outp[(size_t)row * 64 + lane] = __float2bfloat16(dinv[row] * acc[r]);
    }
}

// ---------------------------------------------------------------------------
// CSR gather, 8-way ILP: one wave per node, lane = feature dim.
// hs rows are bf16 (128B/row -> 1 line per random gather). Accumulate f32.
// acc = hs[r] (self-loop) + sum over neighbors; FIN applies final dinv[r].
// ---------------------------------------------------------------------------
template <bool FIN>
__global__ __launch_bounds__(256) void k_gather(const __hip_bfloat16* __restrict__ hs,
                                                const unsigned* __restrict__ offs,
                                                const int* __restrict__ perm,
                                                const float* __restrict__ dinv,
                                                float* __restrict__ outb,
                                                int n, int nE) {
    int lane = threadIdx.x & 63;
    int r = blockIdx.x * 4 + (threadIdx.x >> 6);
    if (r >= n) return;
    unsigned beg = offs[r];
    unsigned end = (r + 1 < n) ? offs[r + 1] : (unsigned)nE;
    float a0 = __bfloat162float(hs[(size_t)r * 64 + lane]);   // self-loop term
    float a1 = 0.f, a2 = 0.f, a3 = 0.f, a4 = 0.f, a5 = 0.f, a6 = 0.f, a7 = 0.f;
    for (unsigned e0 = beg; e0 < end; e0 += 64) {
        unsigned c = min(64u, end - e0);
        int sl = (lane < (int)c) ? perm[e0 + lane] : 0;       // coalesced edge read
        unsigned k = 0;
        for (; k + 8 <= c; k += 8) {
            int s0 = __shfl(sl, (int)k);
            int s1 = __shfl(sl, (int)k + 1);
            int s2 = __shfl(sl, (int)k + 2);
            int s3 = __shfl(sl, (int)k + 3);
            int s4 = __shfl(sl, (int)k + 4);
            int s5 = __shfl(sl, (int)k + 5);
            int s6 = __shfl(sl, (int)k + 6);
            int s7 = __shfl(sl, (int)k + 7);
            float v0 = __bfloat162float(hs[(size_t)s0 * 64 + lane]);
            float v1 = __bfloat162float(hs[(size_t)s1 * 64 + lane]);
            float v2 = __bfloat162float(hs[(size_t)s2 * 64 + lane]);
            float v3 = __bfloat162float(hs[(size_t)s3 * 64 + lane]);
            float v4 = __bfloat162float(hs[(size_t)s4 * 64 + lane]);
            float v5 = __bfloat162float(hs[(size_t)s5 * 64 + lane]);
            float v6 = __bfloat162float(hs[(size_t)s6 * 64 + lane]);
            float v7 = __bfloat162float(hs[(size_t)s7 * 64 + lane]);
            a0 += v0; a1 += v1; a2 += v2; a3 += v3;
            a4 += v4; a5 += v5; a6 += v6; a7 += v7;
        }
        for (; k + 4 <= c; k += 4) {
            int s0 = __shfl(sl, (int)k);
            int s1 = __shfl(sl, (int)k + 1);
            int s2 = __shfl(sl, (int)k + 2);
            int s3 = __shfl(sl, (int)k + 3);
            float v0 = __bfloat162float(hs[(size_t)s0 * 64 + lane]);
            float v1 = __bfloat162float(hs[(size_t)s1 * 64 + lane]);
            float v2 = __bfloat162float(hs[(size_t)s2 * 64 + lane]);
            float v3 = __bfloat162float(hs[(size_t)s3 * 64 + lane]);
            a0 += v0; a1 += v1; a2 += v2; a3 += v3;
        }
        for (; k < c; ++k) {
            int s = __shfl(sl, (int)k);
            a0 += __bfloat162float(hs[(size_t)s * 64 + lane]);
        }
    }
    float acc = ((a0 + a1) + (a2 + a3)) + ((a4 + a5) + (a6 + a7));
    if (FIN) acc *= dinv[r];
    outb[(size_t)r * 64 + lane] = acc;
}

// ---------------------------------------------------------------------------
extern "C" void kernel_launch(void* const* d_in, const int* in_sizes, int n_in,
                              void* d_out, int out_size, void* d_ws, size_t ws_size,
                              hipStream_t stream) {
    const float* x  = (const float*)d_in[0];
    const int*   ei = (const int*)d_in[1];
    const float* W1 = (const float*)d_in[2];
    const float* W2 = (const float*)d_in[3];
    float* out = (float*)d_out;

    int n  = in_sizes[0] / IN_DIM;   // 100000
    int nE = in_sizes[1] / 2;        // 1600000
    const int* src = ei;
    const int* dst = ei + nE;

    // workspace carve-up (256B-aligned); d_out doubles as the layer-1 agg buffer
    char* w = (char*)d_ws;
    size_t nAl = ((size_t)n * 4 + 255) & ~(size_t)255;
    float*          dinv     = (float*)w;          w += nAl;
    unsigned*       cnt      = (unsigned*)w;       w += nAl;
    unsigned*       offs     = (unsigned*)w;       w += nAl;
    unsigned*       partials = (unsigned*)w;       w += 4096;
    unsigned short* rank     = (unsigned short*)w; w += ((size_t)nE * 2 + 255) & ~(size_t)255;
    int*            perm     = (int*)w;            w += ((size_t)nE * 4 + 255) & ~(size_t)255;
    __hip_bfloat16* hs       = (__hip_bfloat16*)w; w += (size_t)n * 64 * 2;   // bf16 rows
    float*          agg      = out;                // layer-1 aggregate lives in d_out

    int nb    = (n + SCAN_CHUNK - 1) / SCAN_CHUNK;
    int gE    = (nE + 255) / 256;
    int gN    = (n + 255) / 256;
    int gRow  = (n + 3) / 4;
    int gTile = (n + 31) / 32;

    // --- prologue: degrees + per-edge ranks, node offsets ---
    k_zero<<<gN, 256, 0, stream>>>(cnt, n);
    k_hist2<<<gE, 256, 0, stream>>>(dst, cnt, rank, nE);
    k_scanA<<<nb, 256, 0, stream>>>(cnt, offs, partials, dinv, n);
    k_scanB<<<1, 256, 0, stream>>>(partials, nb);
    k_scanC<<<gN, 256, 0, stream>>>(offs, partials, n);

    // --- layer 1 ---
    k_lin<IN_DIM, false><<<gTile, 256, 0, stream>>>(x, W1, dinv, hs, n);
    k_scat<<<gE, 256, 0, stream>>>(src, dst, rank, offs, perm, nE);
    k_gather<false><<<gRow, 256, 0, stream>>>(hs, offs, perm, dinv, agg, n, nE);

    // --- layer 2 (reuse hs for hs2; final dinv folded into gather) ---
    k_lin<OUT_DIM, true><<<gTile, 256, 0, stream>>>(agg, W2, dinv, hs, n);
    k_gather<true><<<gRow, 256, 0, stream>>>(hs, offs, perm, dinv, out, n, nE);
}

// Round 13
// 251.638 us; speedup vs baseline: 4.3578x; 1.1987x over previous
//
#include <hip/hip_runtime.h>
#include <hip/hip_bf16.h>

#define IN_DIM  128
#define OUT_DIM 64
#define SCAN_CHUNK 1024   // 256 threads x 4 elems

typedef short  bf16x8 __attribute__((ext_vector_type(8)));
typedef float  f32x4  __attribute__((ext_vector_type(4)));

__device__ __forceinline__ unsigned short f2bf(float f) {   // RNE
    unsigned u = __float_as_uint(f);
    u += 0x7fffu + ((u >> 16) & 1u);
    return (unsigned short)(u >> 16);
}
__device__ __forceinline__ float bf2f(unsigned short h) {
    return __uint_as_float((unsigned)h << 16);
}

// ---------------------------------------------------------------------------
// Prologue: degree histogram (also records per-edge rank) -> exclusive scan
// ---------------------------------------------------------------------------
__global__ void k_zero(unsigned* __restrict__ p, int n) {
    int i = blockIdx.x * blockDim.x + threadIdx.x;
    if (i < n) p[i] = 0u;
}

// rank[e] = number of earlier edges with same dst (atomic order; any perm ok)
__global__ void k_hist2(const int* __restrict__ dst, unsigned* __restrict__ cnt,
                        unsigned short* __restrict__ rank, int nE) {
    int e = blockIdx.x * blockDim.x + threadIdx.x;
    if (e < nE) {
        unsigned k = atomicAdd(&cnt[dst[e]], 1u);
        rank[e] = (unsigned short)k;       // sequential write
    }
}

__global__ __launch_bounds__(256) void k_scanA(const unsigned* __restrict__ cnt,
                                               unsigned* __restrict__ offs,
                                               unsigned* __restrict__ partials,
                                               float* __restrict__ dinv, int n) {
    __shared__ unsigned sums[256];
    int base = blockIdx.x * SCAN_CHUNK + threadIdx.x * 4;
    unsigned v[4]; unsigned s = 0;
#pragma unroll
    for (int k = 0; k < 4; ++k) {
        int i = base + k;
        unsigned c = (i < n) ? cnt[i] : 0u;
        if (i < n) dinv[i] = rsqrtf((float)c + 1.0f);   // +1 self-loop
        v[k] = s; s += c;
    }
    sums[threadIdx.x] = s;
    __syncthreads();
    for (int d = 1; d < 256; d <<= 1) {
        unsigned t = (threadIdx.x >= (unsigned)d) ? sums[threadIdx.x - d] : 0u;
        __syncthreads();
        sums[threadIdx.x] += t;
        __syncthreads();
    }
    unsigned excl = sums[threadIdx.x] - s;
#pragma unroll
    for (int k = 0; k < 4; ++k) {
        int i = base + k;
        if (i < n) offs[i] = excl + v[k];
    }
    if (threadIdx.x == 255) partials[blockIdx.x] = sums[255];
}

__global__ void k_scanB(unsigned* __restrict__ partials, int nb) {
    __shared__ unsigned s[256];
    unsigned v = (threadIdx.x < (unsigned)nb) ? partials[threadIdx.x] : 0u;
    s[threadIdx.x] = v;
    __syncthreads();
    for (int d = 1; d < 256; d <<= 1) {
        unsigned t = (threadIdx.x >= (unsigned)d) ? s[threadIdx.x - d] : 0u;
        __syncthreads();
        s[threadIdx.x] += t;
        __syncthreads();
    }
    if (threadIdx.x < (unsigned)nb) partials[threadIdx.x] = s[threadIdx.x] - v;
}

__global__ void k_scanC(unsigned* __restrict__ offs, const unsigned* __restrict__ partials,
                        int n) {
    int i = blockIdx.x * blockDim.x + threadIdx.x;
    if (i < n) offs[i] += partials[i / SCAN_CHUNK];
}

// ---------------------------------------------------------------------------
// Atomic-free edge scatter (LDS-free, high occupancy hides write latency)
// ---------------------------------------------------------------------------
__global__ void k_scat(const int* __restrict__ src, const int* __restrict__ dst,
                       const unsigned short* __restrict__ rank,
                       const unsigned* __restrict__ offs,
                       int* __restrict__ perm, int nE) {
    int e = blockIdx.x * blockDim.x + threadIdx.x;
    if (e < nE) {
        unsigned p = offs[dst[e]] + (unsigned)rank[e];
        __builtin_nontemporal_store(src[e], &perm[p]);
    }
}

// ---------------------------------------------------------------------------
// MFMA linear layer: out[r] = dinv[r] * (f(in[r]) @ W), f = relu(dinv*.) if RELU.
// bf16 hi/lo split of inputs (x ~ hi+lo; products hh+hl+lh -> ~f32 precision).
// Per block: 64 rows, 4 waves x 16-row stripes. A frags global->reg directly
// (lane&15 = row, (lane>>4)*8 = k-offset). W converted once/block to LDS
// transposed+padded bf16 Wt[col][KD+8] (hi & lo). 4 N-tiles x KD/32 k-steps
// x 3 terms of mfma_f32_16x16x32_bf16. C/D: col=lane&15, row=(lane>>4)*4+reg.
// ---------------------------------------------------------------------------
template <int KD, bool RELU>
__global__ __launch_bounds__(256) void k_linm(const float* __restrict__ in,
                                              const float* __restrict__ W,   // [KD][64]
                                              const float* __restrict__ dinv,
                                              unsigned short* __restrict__ outp, int n) {
    constexpr int LDK = KD + 8;              // pad: bank-balance + keep 16B align
    __shared__ unsigned short WH[64 * LDK];  // bf16 hi, transposed [col][k]
    __shared__ unsigned short WL[64 * LDK];  // bf16 lo
    for (int i = threadIdx.x; i < KD * 64; i += 256) {
        int k = i >> 6, c = i & 63;
        float wv = W[i];                     // coalesced
        unsigned short h = f2bf(wv);
        WH[c * LDK + k] = h;
        WL[c * LDK + k] = f2bf(wv - bf2f(h));
    }
    __syncthreads();

    int wid = threadIdx.x >> 6, lane = threadIdx.x & 63;
    int r0 = blockIdx.x * 64 + wid * 16;     // wave's 16-row stripe
    if (r0 >= n + 15 && r0 >= n) { /* fully out-of-range waves still ok */ }

    constexpr int NK = KD / 32;              // k-steps
    int arow = r0 + (lane & 15);
    int ar = arow < n ? arow : (n - 1);      // clamp (stores masked later)
    int k8 = (lane >> 4) * 8;

    // ---- A fragments: load 8 f32 per k-step, split hi/lo bf16 ----
    bf16x8 ah[NK], al[NK];
    {
        const float* rp = in + (size_t)ar * KD;
        float dvin = RELU ? dinv[ar] : 0.f;
#pragma unroll
        for (int ks = 0; ks < NK; ++ks) {
            float4 v0 = *(const float4*)(rp + ks * 32 + k8);
            float4 v1 = *(const float4*)(rp + ks * 32 + k8 + 4);
            float xv[8] = {v0.x, v0.y, v0.z, v0.w, v1.x, v1.y, v1.z, v1.w};
#pragma unroll
            for (int j = 0; j < 8; ++j) {
                float f = xv[j];
                if (RELU) f = fmaxf(dvin * f, 0.f);
                unsigned short h = f2bf(f);
                ah[ks][j] = (short)h;
                al[ks][j] = (short)f2bf(f - bf2f(h));
            }
        }
    }

    // ---- MFMA: 4 N-tiles, 3 terms (hh, hl, lh) ----
    f32x4 acc[4];
#pragma unroll
    for (int nt = 0; nt < 4; ++nt) {
        int col = nt * 16 + (lane & 15);
        const unsigned short* bh = &WH[col * LDK + k8];
        const unsigned short* bl = &WL[col * LDK + k8];
        f32x4 a = {0.f, 0.f, 0.f, 0.f};
#pragma unroll
        for (int ks = 0; ks < NK; ++ks) {
            bf16x8 Bh = *(const bf16x8*)(bh + ks * 32);
            bf16x8 Bl = *(const bf16x8*)(bl + ks * 32);
            a = __builtin_amdgcn_mfma_f32_16x16x32_bf16(ah[ks], Bh, a, 0, 0, 0);
            a = __builtin_amdgcn_mfma_f32_16x16x32_bf16(ah[ks], Bl, a, 0, 0, 0);
            a = __builtin_amdgcn_mfma_f32_16x16x32_bf16(al[ks], Bh, a, 0, 0, 0);
        }
        acc[nt] = a;
    }

    // ---- write: row = r0 + (lane>>4)*4 + j, col = nt*16 + (lane&15) ----
    int orow0 = r0 + (lane >> 4) * 4;
#pragma unroll
    for (int j = 0; j < 4; ++j) {
        int row = orow0 + j;
        if (row < n) {
            float dv = dinv[row];
#pragma unroll
            for (int nt = 0; nt < 4; ++nt)
                outp[(size_t)row * 64 + nt * 16 + (lane & 15)] = f2bf(dv * acc[nt][j]);
        }
    }
}

// ---------------------------------------------------------------------------
// CSR gather, 8-way ILP: one wave per node, lane = feature dim.
// hs rows are bf16 (128B/row -> 1 line per random gather). Accumulate f32.
// acc = hs[r] (self-loop) + sum over neighbors; FIN applies final dinv[r].
// ---------------------------------------------------------------------------
template <bool FIN>
__global__ __launch_bounds__(256) void k_gather(const __hip_bfloat16* __restrict__ hs,
                                                const unsigned* __restrict__ offs,
                                                const int* __restrict__ perm,
                                                const float* __restrict__ dinv,
                                                float* __restrict__ outb,
                                                int n, int nE) {
    int lane = threadIdx.x & 63;
    int r = blockIdx.x * 4 + (threadIdx.x >> 6);
    if (r >= n) return;
    unsigned beg = offs[r];
    unsigned end = (r + 1 < n) ? offs[r + 1] : (unsigned)nE;
    float a0 = __bfloat162float(hs[(size_t)r * 64 + lane]);   // self-loop term
    float a1 = 0.f, a2 = 0.f, a3 = 0.f, a4 = 0.f, a5 = 0.f, a6 = 0.f, a7 = 0.f;
    for (unsigned e0 = beg; e0 < end; e0 += 64) {
        unsigned c = min(64u, end - e0);
        int sl = (lane < (int)c) ? perm[e0 + lane] : 0;       // coalesced edge read
        unsigned k = 0;
        for (; k + 8 <= c; k += 8) {
            int s0 = __shfl(sl, (int)k);
            int s1 = __shfl(sl, (int)k + 1);
            int s2 = __shfl(sl, (int)k + 2);
            int s3 = __shfl(sl, (int)k + 3);
            int s4 = __shfl(sl, (int)k + 4);
            int s5 = __shfl(sl, (int)k + 5);
            int s6 = __shfl(sl, (int)k + 6);
            int s7 = __shfl(sl, (int)k + 7);
            float v0 = __bfloat162float(hs[(size_t)s0 * 64 + lane]);
            float v1 = __bfloat162float(hs[(size_t)s1 * 64 + lane]);
            float v2 = __bfloat162float(hs[(size_t)s2 * 64 + lane]);
            float v3 = __bfloat162float(hs[(size_t)s3 * 64 + lane]);
            float v4 = __bfloat162float(hs[(size_t)s4 * 64 + lane]);
            float v5 = __bfloat162float(hs[(size_t)s5 * 64 + lane]);
            float v6 = __bfloat162float(hs[(size_t)s6 * 64 + lane]);
            float v7 = __bfloat162float(hs[(size_t)s7 * 64 + lane]);
            a0 += v0; a1 += v1; a2 += v2; a3 += v3;
            a4 += v4; a5 += v5; a6 += v6; a7 += v7;
        }
        for (; k + 4 <= c; k += 4) {
            int s0 = __shfl(sl, (int)k);
            int s1 = __shfl(sl, (int)k + 1);
            int s2 = __shfl(sl, (int)k + 2);
            int s3 = __shfl(sl, (int)k + 3);
            float v0 = __bfloat162float(hs[(size_t)s0 * 64 + lane]);
            float v1 = __bfloat162float(hs[(size_t)s1 * 64 + lane]);
            float v2 = __bfloat162float(hs[(size_t)s2 * 64 + lane]);
            float v3 = __bfloat162float(hs[(size_t)s3 * 64 + lane]);
            a0 += v0; a1 += v1; a2 += v2; a3 += v3;
        }
        for (; k < c; ++k) {
            int s = __shfl(sl, (int)k);
            a0 += __bfloat162float(hs[(size_t)s * 64 + lane]);
        }
    }
    float acc = ((a0 + a1) + (a2 + a3)) + ((a4 + a5) + (a6 + a7));
    if (FIN) acc *= dinv[r];
    outb[(size_t)r * 64 + lane] = acc;
}

// ---------------------------------------------------------------------------
extern "C" void kernel_launch(void* const* d_in, const int* in_sizes, int n_in,
                              void* d_out, int out_size, void* d_ws, size_t ws_size,
                              hipStream_t stream) {
    const float* x  = (const float*)d_in[0];
    const int*   ei = (const int*)d_in[1];
    const float* W1 = (const float*)d_in[2];
    const float* W2 = (const float*)d_in[3];
    float* out = (float*)d_out;

    int n  = in_sizes[0] / IN_DIM;   // 100000
    int nE = in_sizes[1] / 2;        // 1600000
    const int* src = ei;
    const int* dst = ei + nE;

    // workspace carve-up (256B-aligned); d_out doubles as the layer-1 agg buffer
    char* w = (char*)d_ws;
    size_t nAl = ((size_t)n * 4 + 255) & ~(size_t)255;
    float*          dinv     = (float*)w;          w += nAl;
    unsigned*       cnt      = (unsigned*)w;       w += nAl;
    unsigned*       offs     = (unsigned*)w;       w += nAl;
    unsigned*       partials = (unsigned*)w;       w += 4096;
    unsigned short* rank     = (unsigned short*)w; w += ((size_t)nE * 2 + 255) & ~(size_t)255;
    int*            perm     = (int*)w;            w += ((size_t)nE * 4 + 255) & ~(size_t)255;
    __hip_bfloat16* hs       = (__hip_bfloat16*)w; w += (size_t)n * 64 * 2;   // bf16 rows
    float*          agg      = out;                // layer-1 aggregate lives in d_out

    int nb   = (n + SCAN_CHUNK - 1) / SCAN_CHUNK;
    int gE   = (nE + 255) / 256;
    int gN   = (n + 255) / 256;
    int gRow = (n + 3) / 4;
    int gMf  = (n + 63) / 64;        // 64 rows per MFMA block

    // --- prologue: degrees + per-edge ranks, node offsets ---
    k_zero<<<gN, 256, 0, stream>>>(cnt, n);
    k_hist2<<<gE, 256, 0, stream>>>(dst, cnt, rank, nE);
    k_scanA<<<nb, 256, 0, stream>>>(cnt, offs, partials, dinv, n);
    k_scanB<<<1, 256, 0, stream>>>(partials, nb);
    k_scanC<<<gN, 256, 0, stream>>>(offs, partials, n);

    // --- layer 1 ---
    k_linm<IN_DIM, false><<<gMf, 256, 0, stream>>>(x, W1, dinv, (unsigned short*)hs, n);
    k_scat<<<gE, 256, 0, stream>>>(src, dst, rank, offs, perm, nE);
    k_gather<false><<<gRow, 256, 0, stream>>>(hs, offs, perm, dinv, agg, n, nE);

    // --- layer 2 (reuse hs for hs2; final dinv folded into gather) ---
    k_linm<OUT_DIM, true><<<gMf, 256, 0, stream>>>(agg, W2, dinv, (unsigned short*)hs, n);
    k_gather<true><<<gRow, 256, 0, stream>>>(hs, offs, perm, dinv, out, n, nE);
}

// Round 14
// 168.940 us; speedup vs baseline: 6.4910x; 1.4895x over previous
//
#include <hip/hip_runtime.h>
#include <hip/hip_bf16.h>

#define IN_DIM  128
#define OUT_DIM 64
#define EPB 4096          // edges per count/partition block
#define NBK_MAX 512       // max coarse buckets (n <= 131072)

typedef short  bf16x8 __attribute__((ext_vector_type(8)));
typedef float  f32x4  __attribute__((ext_vector_type(4)));
typedef unsigned long long u64;

__device__ __forceinline__ unsigned short f2bf(float f) {   // RNE
    unsigned u = __float_as_uint(f);
    u += 0x7fffu + ((u >> 16) & 1u);
    return (unsigned short)(u >> 16);
}
__device__ __forceinline__ float bf2f(unsigned short h) {
    return __uint_as_float((unsigned)h << 16);
}

// ---------------------------------------------------------------------------
// CSR build, two-level LDS counting sort (no global atomics).
// Bucket = dst >> 8 (256 nodes per bucket).
// ---------------------------------------------------------------------------

// Phase 1: per-block coarse histogram -> colcnt[bucket][blk]
__global__ __launch_bounds__(256) void k_cnt(const int* __restrict__ dst,
                                             unsigned* __restrict__ colcnt,
                                             int nE, int nbk, int nblk) {
    __shared__ unsigned h[NBK_MAX];
    for (int b = threadIdx.x; b < NBK_MAX; b += 256) h[b] = 0u;
    __syncthreads();
    int blk = blockIdx.x;
    int e0 = blk * EPB, e1 = min(e0 + EPB, nE);
    for (int e = e0 + threadIdx.x; e < e1; e += 256)
        atomicAdd(&h[dst[e] >> 8], 1u);
    __syncthreads();
    for (int b = threadIdx.x; b < nbk; b += 256)
        colcnt[(size_t)b * nblk + blk] = h[b];
}

// Phase 2a: per-bucket exclusive scan over blocks (in place); totals out.
__global__ __launch_bounds__(512) void k_bsum(unsigned* __restrict__ colcnt,
                                              unsigned* __restrict__ btot,
                                              int nbk, int nblk) {
    __shared__ unsigned s[512];
    int b = blockIdx.x;
    unsigned v = (threadIdx.x < (unsigned)nblk) ? colcnt[(size_t)b * nblk + threadIdx.x] : 0u;
    s[threadIdx.x] = v;
    __syncthreads();
    for (int d = 1; d < 512; d <<= 1) {
        unsigned t = (threadIdx.x >= (unsigned)d) ? s[threadIdx.x - d] : 0u;
        __syncthreads();
        s[threadIdx.x] += t;
        __syncthreads();
    }
    if (threadIdx.x < (unsigned)nblk)
        colcnt[(size_t)b * nblk + threadIdx.x] = s[threadIdx.x] - v;
    if (threadIdx.x == 511) btot[b] = s[511];
}

// Phase 2b: scan bucket totals -> bbase[0..nbk], bbase[nbk] = nE.
__global__ __launch_bounds__(512) void k_btots(const unsigned* __restrict__ btot,
                                               unsigned* __restrict__ bbase,
                                               int nbk, int nE) {
    __shared__ unsigned s[512];
    unsigned v = (threadIdx.x < (unsigned)nbk) ? btot[threadIdx.x] : 0u;
    s[threadIdx.x] = v;
    __syncthreads();
    for (int d = 1; d < 512; d <<= 1) {
        unsigned t = (threadIdx.x >= (unsigned)d) ? s[threadIdx.x - d] : 0u;
        __syncthreads();
        s[threadIdx.x] += t;
        __syncthreads();
    }
    if (threadIdx.x < (unsigned)nbk) bbase[threadIdx.x] = s[threadIdx.x] - v;
    if (threadIdx.x == 0) bbase[nbk] = (unsigned)nE;
}

// Phase 3: partition edges into bucket-grouped u64 records (dst<<32 | src).
// Writes are contiguous runs per (bucket, block) -> sector-dense.
__global__ __launch_bounds__(256) void k_part(const int* __restrict__ src,
                                              const int* __restrict__ dst,
                                              const unsigned* __restrict__ colcnt,
                                              const unsigned* __restrict__ bbase,
                                              u64* __restrict__ ebuf,
                                              int nE, int nbk, int nblk) {
    __shared__ unsigned curs[NBK_MAX];
    int blk = blockIdx.x;
    for (int b = threadIdx.x; b < nbk; b += 256)
        curs[b] = bbase[b] + colcnt[(size_t)b * nblk + blk];
    __syncthreads();
    int e0 = blk * EPB, e1 = min(e0 + EPB, nE);
    for (int e = e0 + threadIdx.x; e < e1; e += 256) {
        int d = dst[e], s = src[e];
        unsigned p = atomicAdd(&curs[d >> 8], 1u);
        ebuf[p] = ((u64)(unsigned)d << 32) | (unsigned)s;
    }
}

// Phase 4: per-bucket fine pass -> offs, dinv, perm.
__global__ __launch_bounds__(256) void k_fine(const u64* __restrict__ ebuf,
                                              const unsigned* __restrict__ bbase,
                                              unsigned* __restrict__ offs,
                                              float* __restrict__ dinv,
                                              int* __restrict__ perm, int n) {
    __shared__ unsigned deg[256], pos[256], cur[256];
    int b = blockIdx.x;
    int node0 = b << 8;
    unsigned ebeg = bbase[b], eend = bbase[b + 1];
    deg[threadIdx.x] = 0u;
    __syncthreads();
    for (unsigned e = ebeg + threadIdx.x; e < eend; e += 256) {
        u64 rec = ebuf[e];
        atomicAdd(&deg[(unsigned)(rec >> 32) & 255u], 1u);
    }
    __syncthreads();
    unsigned v = deg[threadIdx.x];
    pos[threadIdx.x] = v;
    __syncthreads();
    for (int d = 1; d < 256; d <<= 1) {
        unsigned t = (threadIdx.x >= (unsigned)d) ? pos[threadIdx.x - d] : 0u;
        __syncthreads();
        pos[threadIdx.x] += t;
        __syncthreads();
    }
    unsigned excl = pos[threadIdx.x] - v;
    cur[threadIdx.x] = excl;
    int node = node0 + threadIdx.x;
    if (node < n) {
        offs[node] = ebeg + excl;
        dinv[node] = rsqrtf((float)v + 1.0f);    // +1 self-loop
    }
    __syncthreads();
    for (unsigned e = ebeg + threadIdx.x; e < eend; e += 256) {
        u64 rec = ebuf[e];
        unsigned p = atomicAdd(&cur[(unsigned)(rec >> 32) & 255u], 1u);
        perm[ebeg + p] = (int)(unsigned)rec;     // src
    }
}

// ---------------------------------------------------------------------------
// MFMA linear layer (R13-proven): out[r] = dinv[r]*(f(in[r]) @ W), bf16 hi/lo
// split (hh+hl+lh terms ~ f32 precision). 64 rows/block, 4 waves x 16-row
// stripes; W->LDS transposed+padded bf16; mfma_f32_16x16x32_bf16.
// ---------------------------------------------------------------------------
template <int KD, bool RELU>
__global__ __launch_bounds__(256) void k_linm(const float* __restrict__ in,
                                              const float* __restrict__ W,   // [KD][64]
                                              const float* __restrict__ dinv,
                                              unsigned short* __restrict__ outp, int n) {
    constexpr int LDK = KD + 8;
    __shared__ unsigned short WH[64 * LDK];
    __shared__ unsigned short WL[64 * LDK];
    for (int i = threadIdx.x; i < KD * 64; i += 256) {
        int k = i >> 6, c = i & 63;
        float wv = W[i];
        unsigned short h = f2bf(wv);
        WH[c * LDK + k] = h;
        WL[c * LDK + k] = f2bf(wv - bf2f(h));
    }
    __syncthreads();

    int wid = threadIdx.x >> 6, lane = threadIdx.x & 63;
    int r0 = blockIdx.x * 64 + wid * 16;

    constexpr int NK = KD / 32;
    int arow = r0 + (lane & 15);
    int ar = arow < n ? arow : (n - 1);
    int k8 = (lane >> 4) * 8;

    bf16x8 ah[NK], al[NK];
    {
        const float* rp = in + (size_t)ar * KD;
        float dvin = RELU ? dinv[ar] : 0.f;
#pragma unroll
        for (int ks = 0; ks < NK; ++ks) {
            float4 v0 = *(const float4*)(rp + ks * 32 + k8);
            float4 v1 = *(const float4*)(rp + ks * 32 + k8 + 4);
            float xv[8] = {v0.x, v0.y, v0.z, v0.w, v1.x, v1.y, v1.z, v1.w};
#pragma unroll
            for (int j = 0; j < 8; ++j) {
                float f = xv[j];
                if (RELU) f = fmaxf(dvin * f, 0.f);
                unsigned short h = f2bf(f);
                ah[ks][j] = (short)h;
                al[ks][j] = (short)f2bf(f - bf2f(h));
            }
        }
    }

    f32x4 acc[4];
#pragma unroll
    for (int nt = 0; nt < 4; ++nt) {
        int col = nt * 16 + (lane & 15);
        const unsigned short* bh = &WH[col * LDK + k8];
        const unsigned short* bl = &WL[col * LDK + k8];
        f32x4 a = {0.f, 0.f, 0.f, 0.f};
#pragma unroll
        for (int ks = 0; ks < NK; ++ks) {
            bf16x8 Bh = *(const bf16x8*)(bh + ks * 32);
            bf16x8 Bl = *(const bf16x8*)(bl + ks * 32);
            a = __builtin_amdgcn_mfma_f32_16x16x32_bf16(ah[ks], Bh, a, 0, 0, 0);
            a = __builtin_amdgcn_mfma_f32_16x16x32_bf16(ah[ks], Bl, a, 0, 0, 0);
            a = __builtin_amdgcn_mfma_f32_16x16x32_bf16(al[ks], Bh, a, 0, 0, 0);
        }
        acc[nt] = a;
    }

    int orow0 = r0 + (lane >> 4) * 4;
#pragma unroll
    for (int j = 0; j < 4; ++j) {
        int row = orow0 + j;
        if (row < n) {
            float dv = dinv[row];
#pragma unroll
            for (int nt = 0; nt < 4; ++nt)
                outp[(size_t)row * 64 + nt * 16 + (lane & 15)] = f2bf(dv * acc[nt][j]);
        }
    }
}

// ---------------------------------------------------------------------------
// CSR gather, 8-way ILP (R12/R13-proven): one wave per node, lane = feature.
// hs rows bf16 (128B). acc = hs[r] + sum neighbors; FIN applies final dinv.
// ---------------------------------------------------------------------------
template <bool FIN>
__global__ __launch_bounds__(256) void k_gather(const __hip_bfloat16* __restrict__ hs,
                                                const unsigned* __restrict__ offs,
                                                const int* __restrict__ perm,
                                                const float* __restrict__ dinv,
                                                float* __restrict__ outb,
                                                int n, int nE) {
    int lane = threadIdx.x & 63;
    int r = blockIdx.x * 4 + (threadIdx.x >> 6);
    if (r >= n) return;
    unsigned beg = offs[r];
    unsigned end = (r + 1 < n) ? offs[r + 1] : (unsigned)nE;
    float a0 = __bfloat162float(hs[(size_t)r * 64 + lane]);   // self-loop term
    float a1 = 0.f, a2 = 0.f, a3 = 0.f, a4 = 0.f, a5 = 0.f, a6 = 0.f, a7 = 0.f;
    for (unsigned e0 = beg; e0 < end; e0 += 64) {
        unsigned c = min(64u, end - e0);
        int sl = (lane < (int)c) ? perm[e0 + lane] : 0;       // coalesced edge read
        unsigned k = 0;
        for (; k + 8 <= c; k += 8) {
            int s0 = __shfl(sl, (int)k);
            int s1 = __shfl(sl, (int)k + 1);
            int s2 = __shfl(sl, (int)k + 2);
            int s3 = __shfl(sl, (int)k + 3);
            int s4 = __shfl(sl, (int)k + 4);
            int s5 = __shfl(sl, (int)k + 5);
            int s6 = __shfl(sl, (int)k + 6);
            int s7 = __shfl(sl, (int)k + 7);
            float v0 = __bfloat162float(hs[(size_t)s0 * 64 + lane]);
            float v1 = __bfloat162float(hs[(size_t)s1 * 64 + lane]);
            float v2 = __bfloat162float(hs[(size_t)s2 * 64 + lane]);
            float v3 = __bfloat162float(hs[(size_t)s3 * 64 + lane]);
            float v4 = __bfloat162float(hs[(size_t)s4 * 64 + lane]);
            float v5 = __bfloat162float(hs[(size_t)s5 * 64 + lane]);
            float v6 = __bfloat162float(hs[(size_t)s6 * 64 + lane]);
            float v7 = __bfloat162float(hs[(size_t)s7 * 64 + lane]);
            a0 += v0; a1 += v1; a2 += v2; a3 += v3;
            a4 += v4; a5 += v5; a6 += v6; a7 += v7;
        }
        for (; k + 4 <= c; k += 4) {
            int s0 = __shfl(sl, (int)k);
            int s1 = __shfl(sl, (int)k + 1);
            int s2 = __shfl(sl, (int)k + 2);
            int s3 = __shfl(sl, (int)k + 3);
            float v0 = __bfloat162float(hs[(size_t)s0 * 64 + lane]);
            float v1 = __bfloat162float(hs[(size_t)s1 * 64 + lane]);
            float v2 = __bfloat162float(hs[(size_t)s2 * 64 + lane]);
            float v3 = __bfloat162float(hs[(size_t)s3 * 64 + lane]);
            a0 += v0; a1 += v1; a2 += v2; a3 += v3;
        }
        for (; k < c; ++k) {
            int s = __shfl(sl, (int)k);
            a0 += __bfloat162float(hs[(size_t)s * 64 + lane]);
        }
    }
    float acc = ((a0 + a1) + (a2 + a3)) + ((a4 + a5) + (a6 + a7));
    if (FIN) acc *= dinv[r];
    outb[(size_t)r * 64 + lane] = acc;
}

// ---------------------------------------------------------------------------
extern "C" void kernel_launch(void* const* d_in, const int* in_sizes, int n_in,
                              void* d_out, int out_size, void* d_ws, size_t ws_size,
                              hipStream_t stream) {
    const float* x  = (const float*)d_in[0];
    const int*   ei = (const int*)d_in[1];
    const float* W1 = (const float*)d_in[2];
    const float* W2 = (const float*)d_in[3];
    float* out = (float*)d_out;

    int n  = in_sizes[0] / IN_DIM;   // 100000
    int nE = in_sizes[1] / 2;        // 1600000
    const int* src = ei;
    const int* dst = ei + nE;

    int nbk  = (n + 255) >> 8;               // coarse buckets (391)
    int nblk = (nE + EPB - 1) / EPB;         // count/partition blocks (391)

    // workspace carve-up (256B-aligned); d_out doubles as the layer-1 agg buffer
    char* w = (char*)d_ws;
    size_t nAl = ((size_t)n * 4 + 255) & ~(size_t)255;
    float*          dinv   = (float*)w;     w += nAl;
    unsigned*       offs   = (unsigned*)w;  w += nAl;
    unsigned*       colcnt = (unsigned*)w;  w += ((size_t)nbk * nblk * 4 + 255) & ~(size_t)255;
    unsigned*       btot   = (unsigned*)w;  w += ((size_t)nbk * 4 + 255) & ~(size_t)255;
    unsigned*       bbase  = (unsigned*)w;  w += ((size_t)(nbk + 1) * 4 + 255) & ~(size_t)255;
    u64*            ebuf   = (u64*)w;       w += ((size_t)nE * 8 + 255) & ~(size_t)255;
    int*            perm   = (int*)w;       w += ((size_t)nE * 4 + 255) & ~(size_t)255;
    __hip_bfloat16* hs     = (__hip_bfloat16*)w; w += (size_t)n * 64 * 2;
    float*          agg    = out;            // layer-1 aggregate lives in d_out

    int gRow = (n + 3) / 4;
    int gMf  = (n + 63) / 64;

    // --- CSR build: two-level LDS counting sort ---
    k_cnt  <<<nblk, 256, 0, stream>>>(dst, colcnt, nE, nbk, nblk);
    k_bsum <<<nbk,  512, 0, stream>>>(colcnt, btot, nbk, nblk);
    k_btots<<<1,    512, 0, stream>>>(btot, bbase, nbk, nE);
    k_part <<<nblk, 256, 0, stream>>>(src, dst, colcnt, bbase, ebuf, nE, nbk, nblk);
    k_fine <<<nbk,  256, 0, stream>>>(ebuf, bbase, offs, dinv, perm, n);

    // --- layer 1 ---
    k_linm<IN_DIM, false><<<gMf, 256, 0, stream>>>(x, W1, dinv, (unsigned short*)hs, n);
    k_gather<false><<<gRow, 256, 0, stream>>>(hs, offs, perm, dinv, agg, n, nE);

    // --- layer 2 (reuse hs; final dinv folded into gather) ---
    k_linm<OUT_DIM, true><<<gMf, 256, 0, stream>>>(agg, W2, dinv, (unsigned short*)hs, n);
    k_gather<true><<<gRow, 256, 0, stream>>>(hs, offs, perm, dinv, out, n, nE);
}

// Round 15
// 165.122 us; speedup vs baseline: 6.6410x; 1.0231x over previous
//
#include <hip/hip_runtime.h>
#include <hip/hip_bf16.h>

#define IN_DIM  128
#define OUT_DIM 64
#define EPB 4096          // edges per count/partition block
#define NBK_MAX 512       // max coarse buckets (n <= 131072)

typedef short  bf16x8 __attribute__((ext_vector_type(8)));
typedef float  f32x4  __attribute__((ext_vector_type(4)));
typedef unsigned long long u64;

__device__ __forceinline__ unsigned short f2bf(float f) {   // RNE
    unsigned u = __float_as_uint(f);
    u += 0x7fffu + ((u >> 16) & 1u);
    return (unsigned short)(u >> 16);
}
__device__ __forceinline__ float bf2f(unsigned short h) {
    return __uint_as_float((unsigned)h << 16);
}

// ---------------------------------------------------------------------------
// CSR build, two-level LDS counting sort (no global atomics).
// Bucket = dst >> 8 (256 nodes per bucket).
// ---------------------------------------------------------------------------

// Phase 1: per-block coarse histogram -> colcnt[bucket][blk]
__global__ __launch_bounds__(256) void k_cnt(const int* __restrict__ dst,
                                             unsigned* __restrict__ colcnt,
                                             int nE, int nbk, int nblk) {
    __shared__ unsigned h[NBK_MAX];
    for (int b = threadIdx.x; b < NBK_MAX; b += 256) h[b] = 0u;
    __syncthreads();
    int blk = blockIdx.x;
    int e0 = blk * EPB, e1 = min(e0 + EPB, nE);
    for (int e = e0 + threadIdx.x; e < e1; e += 256)
        atomicAdd(&h[dst[e] >> 8], 1u);
    __syncthreads();
    for (int b = threadIdx.x; b < nbk; b += 256)
        colcnt[(size_t)b * nblk + blk] = h[b];
}

// Phase 2a: per-bucket exclusive scan over blocks (in place); totals out.
__global__ __launch_bounds__(512) void k_bsum(unsigned* __restrict__ colcnt,
                                              unsigned* __restrict__ btot,
                                              int nbk, int nblk) {
    __shared__ unsigned s[512];
    int b = blockIdx.x;
    unsigned v = (threadIdx.x < (unsigned)nblk) ? colcnt[(size_t)b * nblk + threadIdx.x] : 0u;
    s[threadIdx.x] = v;
    __syncthreads();
    for (int d = 1; d < 512; d <<= 1) {
        unsigned t = (threadIdx.x >= (unsigned)d) ? s[threadIdx.x - d] : 0u;
        __syncthreads();
        s[threadIdx.x] += t;
        __syncthreads();
    }
    if (threadIdx.x < (unsigned)nblk)
        colcnt[(size_t)b * nblk + threadIdx.x] = s[threadIdx.x] - v;
    if (threadIdx.x == 511) btot[b] = s[511];
}

// Phase 2b: scan bucket totals -> bbase[0..nbk], bbase[nbk] = nE.
__global__ __launch_bounds__(512) void k_btots(const unsigned* __restrict__ btot,
                                               unsigned* __restrict__ bbase,
                                               int nbk, int nE) {
    __shared__ unsigned s[512];
    unsigned v = (threadIdx.x < (unsigned)nbk) ? btot[threadIdx.x] : 0u;
    s[threadIdx.x] = v;
    __syncthreads();
    for (int d = 1; d < 512; d <<= 1) {
        unsigned t = (threadIdx.x >= (unsigned)d) ? s[threadIdx.x - d] : 0u;
        __syncthreads();
        s[threadIdx.x] += t;
        __syncthreads();
    }
    if (threadIdx.x < (unsigned)nbk) bbase[threadIdx.x] = s[threadIdx.x] - v;
    if (threadIdx.x == 0) bbase[nbk] = (unsigned)nE;
}

// Phase 3: partition edges into bucket-grouped u64 records (dst<<32 | src).
__global__ __launch_bounds__(256) void k_part(const int* __restrict__ src,
                                              const int* __restrict__ dst,
                                              const unsigned* __restrict__ colcnt,
                                              const unsigned* __restrict__ bbase,
                                              u64* __restrict__ ebuf,
                                              int nE, int nbk, int nblk) {
    __shared__ unsigned curs[NBK_MAX];
    int blk = blockIdx.x;
    for (int b = threadIdx.x; b < nbk; b += 256)
        curs[b] = bbase[b] + colcnt[(size_t)b * nblk + blk];
    __syncthreads();
    int e0 = blk * EPB, e1 = min(e0 + EPB, nE);
    for (int e = e0 + threadIdx.x; e < e1; e += 256) {
        int d = dst[e], s = src[e];
        unsigned p = atomicAdd(&curs[d >> 8], 1u);
        ebuf[p] = ((u64)(unsigned)d << 32) | (unsigned)s;
    }
}

// Phase 4: per-bucket fine pass -> offs, dinv, perm.
__global__ __launch_bounds__(256) void k_fine(const u64* __restrict__ ebuf,
                                              const unsigned* __restrict__ bbase,
                                              unsigned* __restrict__ offs,
                                              float* __restrict__ dinv,
                                              int* __restrict__ perm, int n) {
    __shared__ unsigned deg[256], pos[256], cur[256];
    int b = blockIdx.x;
    int node0 = b << 8;
    unsigned ebeg = bbase[b], eend = bbase[b + 1];
    deg[threadIdx.x] = 0u;
    __syncthreads();
    for (unsigned e = ebeg + threadIdx.x; e < eend; e += 256) {
        u64 rec = ebuf[e];
        atomicAdd(&deg[(unsigned)(rec >> 32) & 255u], 1u);
    }
    __syncthreads();
    unsigned v = deg[threadIdx.x];
    pos[threadIdx.x] = v;
    __syncthreads();
    for (int d = 1; d < 256; d <<= 1) {
        unsigned t = (threadIdx.x >= (unsigned)d) ? pos[threadIdx.x - d] : 0u;
        __syncthreads();
        pos[threadIdx.x] += t;
        __syncthreads();
    }
    unsigned excl = pos[threadIdx.x] - v;
    cur[threadIdx.x] = excl;
    int node = node0 + threadIdx.x;
    if (node < n) {
        offs[node] = ebeg + excl;
        dinv[node] = rsqrtf((float)v + 1.0f);    // +1 self-loop
    }
    __syncthreads();
    for (unsigned e = ebeg + threadIdx.x; e < eend; e += 256) {
        u64 rec = ebuf[e];
        unsigned p = atomicAdd(&cur[(unsigned)(rec >> 32) & 255u], 1u);
        perm[ebeg + p] = (int)(unsigned)rec;     // src
    }
}

// ---------------------------------------------------------------------------
// MFMA linear layer (R13-proven): out[r] = dinv[r]*(f(in[r]) @ W), bf16 hi/lo
// split (hh+hl+lh terms ~ f32 precision). 64 rows/block, 4 waves x 16-row
// stripes; W->LDS transposed+padded bf16; mfma_f32_16x16x32_bf16.
// ---------------------------------------------------------------------------
template <int KD, bool RELU>
__global__ __launch_bounds__(256) void k_linm(const float* __restrict__ in,
                                              const float* __restrict__ W,   // [KD][64]
                                              const float* __restrict__ dinv,
                                              unsigned short* __restrict__ outp, int n) {
    constexpr int LDK = KD + 8;
    __shared__ unsigned short WH[64 * LDK];
    __shared__ unsigned short WL[64 * LDK];
    for (int i = threadIdx.x; i < KD * 64; i += 256) {
        int k = i >> 6, c = i & 63;
        float wv = W[i];
        unsigned short h = f2bf(wv);
        WH[c * LDK + k] = h;
        WL[c * LDK + k] = f2bf(wv - bf2f(h));
    }
    __syncthreads();

    int wid = threadIdx.x >> 6, lane = threadIdx.x & 63;
    int r0 = blockIdx.x * 64 + wid * 16;

    constexpr int NK = KD / 32;
    int arow = r0 + (lane & 15);
    int ar = arow < n ? arow : (n - 1);
    int k8 = (lane >> 4) * 8;

    bf16x8 ah[NK], al[NK];
    {
        const float* rp = in + (size_t)ar * KD;
        float dvin = RELU ? dinv[ar] : 0.f;
#pragma unroll
        for (int ks = 0; ks < NK; ++ks) {
            float4 v0 = *(const float4*)(rp + ks * 32 + k8);
            float4 v1 = *(const float4*)(rp + ks * 32 + k8 + 4);
            float xv[8] = {v0.x, v0.y, v0.z, v0.w, v1.x, v1.y, v1.z, v1.w};
#pragma unroll
            for (int j = 0; j < 8; ++j) {
                float f = xv[j];
                if (RELU) f = fmaxf(dvin * f, 0.f);
                unsigned short h = f2bf(f);
                ah[ks][j] = (short)h;
                al[ks][j] = (short)f2bf(f - bf2f(h));
            }
        }
    }

    f32x4 acc[4];
#pragma unroll
    for (int nt = 0; nt < 4; ++nt) {
        int col = nt * 16 + (lane & 15);
        const unsigned short* bh = &WH[col * LDK + k8];
        const unsigned short* bl = &WL[col * LDK + k8];
        f32x4 a = {0.f, 0.f, 0.f, 0.f};
#pragma unroll
        for (int ks = 0; ks < NK; ++ks) {
            bf16x8 Bh = *(const bf16x8*)(bh + ks * 32);
            bf16x8 Bl = *(const bf16x8*)(bl + ks * 32);
            a = __builtin_amdgcn_mfma_f32_16x16x32_bf16(ah[ks], Bh, a, 0, 0, 0);
            a = __builtin_amdgcn_mfma_f32_16x16x32_bf16(ah[ks], Bl, a, 0, 0, 0);
            a = __builtin_amdgcn_mfma_f32_16x16x32_bf16(al[ks], Bh, a, 0, 0, 0);
        }
        acc[nt] = a;
    }

    int orow0 = r0 + (lane >> 4) * 4;
#pragma unroll
    for (int j = 0; j < 4; ++j) {
        int row = orow0 + j;
        if (row < n) {
            float dv = dinv[row];
#pragma unroll
            for (int nt = 0; nt < 4; ++nt)
                outp[(size_t)row * 64 + nt * 16 + (lane & 15)] = f2bf(dv * acc[nt][j]);
        }
    }
}

// ---------------------------------------------------------------------------
// CSR gather, 4-rows-per-load: wave = 4 groups x 16 lanes; group g handles
// edge k+g, lane li reads features li*4..li*4+3 (ushort4, 8B) -> one load
// instruction fetches 4 complete 128B rows. 16-edge unroll (4 acc quads).
// Cross-group combine via shfl_xor(16/32); group 0 stores the 256B row.
// ---------------------------------------------------------------------------
template <bool FIN>
__global__ __launch_bounds__(256) void k_gather(const unsigned short* __restrict__ hs,
                                                const unsigned* __restrict__ offs,
                                                const int* __restrict__ perm,
                                                const float* __restrict__ dinv,
                                                float* __restrict__ outb,
                                                int n, int nE) {
    int lane = threadIdx.x & 63;
    int g = lane >> 4, li = lane & 15;
    int r = blockIdx.x * 4 + (threadIdx.x >> 6);
    if (r >= n) return;
    unsigned beg = offs[r];
    unsigned end = (r + 1 < n) ? offs[r + 1] : (unsigned)nE;

    float4 a0 = {0.f, 0.f, 0.f, 0.f}, a1 = a0, a2 = a0, a3 = a0;
    if (g == 0) {                       // self-loop term (once)
        ushort4 sv = *(const ushort4*)(hs + (size_t)r * 64 + li * 4);
        a0.x = bf2f(sv.x); a0.y = bf2f(sv.y); a0.z = bf2f(sv.z); a0.w = bf2f(sv.w);
    }

    for (unsigned e0 = beg; e0 < end; e0 += 64) {
        unsigned c = min(64u, end - e0);
        int sl = (lane < (int)c) ? perm[e0 + lane] : 0;   // coalesced edge read
        unsigned k = 0;
        for (; k + 16 <= c; k += 16) {                    // 16 edges: 4 loads/lane
            int s0 = __shfl(sl, (int)(k + g));
            int s1 = __shfl(sl, (int)(k + 4 + g));
            int s2 = __shfl(sl, (int)(k + 8 + g));
            int s3 = __shfl(sl, (int)(k + 12 + g));
            ushort4 v0 = *(const ushort4*)(hs + (size_t)s0 * 64 + li * 4);
            ushort4 v1 = *(const ushort4*)(hs + (size_t)s1 * 64 + li * 4);
            ushort4 v2 = *(const ushort4*)(hs + (size_t)s2 * 64 + li * 4);
            ushort4 v3 = *(const ushort4*)(hs + (size_t)s3 * 64 + li * 4);
            a0.x += bf2f(v0.x); a0.y += bf2f(v0.y); a0.z += bf2f(v0.z); a0.w += bf2f(v0.w);
            a1.x += bf2f(v1.x); a1.y += bf2f(v1.y); a1.z += bf2f(v1.z); a1.w += bf2f(v1.w);
            a2.x += bf2f(v2.x); a2.y += bf2f(v2.y); a2.z += bf2f(v2.z); a2.w += bf2f(v2.w);
            a3.x += bf2f(v3.x); a3.y += bf2f(v3.y); a3.z += bf2f(v3.z); a3.w += bf2f(v3.w);
        }
        for (; k < c; k += 4) {                           // 4-edge tail, predicated
            int idx = (int)k + g;
            bool val = idx < (int)c;
            int s = __shfl(sl, val ? idx : 0);
            ushort4 v = *(const ushort4*)(hs + (size_t)s * 64 + li * 4);
            if (val) {
                a0.x += bf2f(v.x); a0.y += bf2f(v.y);
                a0.z += bf2f(v.z); a0.w += bf2f(v.w);
            }
        }
    }

    float4 acc;
    acc.x = (a0.x + a1.x) + (a2.x + a3.x);
    acc.y = (a0.y + a1.y) + (a2.y + a3.y);
    acc.z = (a0.z + a1.z) + (a2.z + a3.z);
    acc.w = (a0.w + a1.w) + (a2.w + a3.w);
    // combine the 4 lane-groups (bits 4,5 of lane)
    acc.x += __shfl_xor(acc.x, 16); acc.x += __shfl_xor(acc.x, 32);
    acc.y += __shfl_xor(acc.y, 16); acc.y += __shfl_xor(acc.y, 32);
    acc.z += __shfl_xor(acc.z, 16); acc.z += __shfl_xor(acc.z, 32);
    acc.w += __shfl_xor(acc.w, 16); acc.w += __shfl_xor(acc.w, 32);

    if (g == 0) {
        if (FIN) {
            float dv = dinv[r];
            acc.x *= dv; acc.y *= dv; acc.z *= dv; acc.w *= dv;
        }
        *(float4*)(outb + (size_t)r * 64 + li * 4) = acc;   // 16 lanes x 16B = 256B row
    }
}

// ---------------------------------------------------------------------------
extern "C" void kernel_launch(void* const* d_in, const int* in_sizes, int n_in,
                              void* d_out, int out_size, void* d_ws, size_t ws_size,
                              hipStream_t stream) {
    const float* x  = (const float*)d_in[0];
    const int*   ei = (const int*)d_in[1];
    const float* W1 = (const float*)d_in[2];
    const float* W2 = (const float*)d_in[3];
    float* out = (float*)d_out;

    int n  = in_sizes[0] / IN_DIM;   // 100000
    int nE = in_sizes[1] / 2;        // 1600000
    const int* src = ei;
    const int* dst = ei + nE;

    int nbk  = (n + 255) >> 8;               // coarse buckets (391)
    int nblk = (nE + EPB - 1) / EPB;         // count/partition blocks (391)

    // workspace carve-up (256B-aligned); d_out doubles as the layer-1 agg buffer
    char* w = (char*)d_ws;
    size_t nAl = ((size_t)n * 4 + 255) & ~(size_t)255;
    float*          dinv   = (float*)w;     w += nAl;
    unsigned*       offs   = (unsigned*)w;  w += nAl;
    unsigned*       colcnt = (unsigned*)w;  w += ((size_t)nbk * nblk * 4 + 255) & ~(size_t)255;
    unsigned*       btot   = (unsigned*)w;  w += ((size_t)nbk * 4 + 255) & ~(size_t)255;
    unsigned*       bbase  = (unsigned*)w;  w += ((size_t)(nbk + 1) * 4 + 255) & ~(size_t)255;
    u64*            ebuf   = (u64*)w;       w += ((size_t)nE * 8 + 255) & ~(size_t)255;
    int*            perm   = (int*)w;       w += ((size_t)nE * 4 + 255) & ~(size_t)255;
    unsigned short* hs     = (unsigned short*)w; w += (size_t)n * 64 * 2;
    float*          agg    = out;            // layer-1 aggregate lives in d_out

    int gRow = (n + 3) / 4;
    int gMf  = (n + 63) / 64;

    // --- CSR build: two-level LDS counting sort ---
    k_cnt  <<<nblk, 256, 0, stream>>>(dst, colcnt, nE, nbk, nblk);
    k_bsum <<<nbk,  512, 0, stream>>>(colcnt, btot, nbk, nblk);
    k_btots<<<1,    512, 0, stream>>>(btot, bbase, nbk, nE);
    k_part <<<nblk, 256, 0, stream>>>(src, dst, colcnt, bbase, ebuf, nE, nbk, nblk);
    k_fine <<<nbk,  256, 0, stream>>>(ebuf, bbase, offs, dinv, perm, n);

    // --- layer 1 ---
    k_linm<IN_DIM, false><<<gMf, 256, 0, stream>>>(x, W1, dinv, hs, n);
    k_gather<false><<<gRow, 256, 0, stream>>>(hs, offs, perm, dinv, agg, n, nE);

    // --- layer 2 (reuse hs; final dinv folded into gather) ---
    k_linm<OUT_DIM, true><<<gMf, 256, 0, stream>>>(agg, W2, dinv, hs, n);
    k_gather<true><<<gRow, 256, 0, stream>>>(hs, offs, perm, dinv, out, n, nE);
}